// Round 8
// baseline (14.905 us; speedup 1.0000x reference)
//
#include <hip/hip_runtime.h>

// 14-qubit statevector sim, batch 256 — rank-2 separable collapsed form,
// two-kernel split: table build (per batch) + fill-shaped streaming readout.
//
// Validated math (rounds 0-7, absmax <= 4.9e-4 vs 8.67e-3 threshold):
//   s0 = product state (fused initial-RY + layer-0 RY/RZ/RY per qubit),
//   CNOT chain == Gray map g(l) = l ^ (l>>1), layer-1 fuses to one 2x2 per qubit,
//   final state rank-2 separable:
//     s2[m_hi,m_lo] = d0[m_hi] c0[m_lo] + d1[m_hi] c1[m_lo]
//   c_p/d_p: 128-vectors via 7 butterfly levels in one wave (__shfl_xor).
//   Readout: out[A*128+m] = e(A) . f(m ^ 127*(A&1))   (4 real FMAs)
//
// ws layout per batch (1024 floats = 4 KB, 1 MB total):
//   [  0..128) fjx   [128..256) fjy   [256..384) fjz   [384..512) fjw
//   [512..1024) eA as float4[128]

typedef float f32x2 __attribute__((ext_vector_type(2)));
typedef float f32x4 __attribute__((ext_vector_type(4)));

constexpr int NQ  = 14;
constexpr int DIM = 1 << NQ;       // 16384

__device__ __forceinline__ f32x2 cmul(f32x2 a, f32x2 b) {
    return f32x2{a.x * b.x - a.y * b.y, a.x * b.y + a.y * b.x};
}
__device__ __forceinline__ int g7(int x)  { return x ^ (x >> 1); }
__device__ __forceinline__ int g7i(int x) { x ^= x >> 1; x ^= x >> 2; x ^= x >> 4; return x; }

// ---------------- kernel 1: per-batch readout tables (4 KB each) ----------------
__global__ __launch_bounds__(256)
void qtab_kernel(const float* __restrict__ latent,
                 const float* __restrict__ weights,
                 float* __restrict__ ws)
{
    __shared__ f32x2 vq [2 * NQ];
    __shared__ f32x2 m1 [4 * NQ];
    __shared__ f32x2 plo[128], phi[128];
    __shared__ f32x2 cc0[128], cc1[128], dd0[128], dd1[128];

    const int b   = blockIdx.x;
    const int tid = threadIdx.x;

    // ---- Phase A: fused per-qubit gate parameters ----
    if (tid < NQ) {
        const int q = tid;
        const float a = weights[3 * q] + 3.14159265358979323846f * latent[b * NQ + q];
        const float t = weights[3 * q + 1];
        const float c = weights[3 * q + 2];
        float ct, stt, cp, sp, cm, sm;
        __sincosf(0.5f * t, &stt, &ct);
        __sincosf(0.5f * (a + c), &sp, &cp);
        __sincosf(0.5f * (a - c), &sm, &cm);
        vq[2 * q + 0] = f32x2{ct * cp, -stt * cm};
        vq[2 * q + 1] = f32x2{ct * sp,  stt * sm};
    } else if (tid >= 64 && tid < 64 + NQ) {
        const int q = tid - 64;
        const float a = weights[3 * NQ + 3 * q];
        const float t = weights[3 * NQ + 3 * q + 1];
        const float c = weights[3 * NQ + 3 * q + 2];
        float ct, stt, cp, sp, cm, sm;
        __sincosf(0.5f * t, &stt, &ct);
        __sincosf(0.5f * (a + c), &sp, &cp);
        __sincosf(0.5f * (a - c), &sm, &cm);
        m1[4 * q + 0] = f32x2{ ct * cp, -stt * cm};
        m1[4 * q + 1] = f32x2{-ct * sp,  stt * sm};
        m1[4 * q + 2] = f32x2{ ct * sp,  stt * sm};
        m1[4 * q + 3] = f32x2{ ct * cp,  stt * cm};
    }
    __syncthreads();

    // ---- Phase B: product tables ----
    {
        const int half = tid >> 7;
        const int m    = tid & 127;
        const int qb   = half * 7;
        f32x2 p = {1.0f, 0.0f};
        #pragma unroll
        for (int j = 0; j < 7; ++j)
            p = cmul(p, vq[2 * (qb + j) + ((m >> j) & 1)]);
        (half ? phi : plo)[m] = p;
    }
    __syncthreads();

    // ---- Phase C: four 128-vector butterfly pipelines, one per wave ----
    {
        const int w    = tid >> 6;       // 0:c0 1:c1 2:d0 3:d1
        const int lane = tid & 63;
        const int u0 = 2 * lane, u1 = 2 * lane + 1;

        f32x2 r0, r1;
        if (w == 0)      { r0 = plo[g7(u0)];       r1 = plo[g7(u1)];       }
        else if (w == 1) { r0 = plo[g7(u0) ^ 64];  r1 = plo[g7(u1) ^ 64];  }
        else if (w == 2) { r0 = phi[g7(u0)];       r1 = f32x2{0.f, 0.f};   }
        else             { r0 = f32x2{0.f, 0.f};   r1 = phi[g7(u1)];       }

        const int mbase = (w >> 1) * 7;

        {   // level 0: bit 0 of u lives in-register
            const f32x2 M00 = m1[4 * mbase + 0], M01 = m1[4 * mbase + 1];
            const f32x2 M10 = m1[4 * mbase + 2], M11 = m1[4 * mbase + 3];
            const f32x2 n0 = cmul(M00, r0) + cmul(M01, r1);
            const f32x2 n1 = cmul(M10, r0) + cmul(M11, r1);
            r0 = n0; r1 = n1;
        }
        #pragma unroll
        for (int k = 1; k < 7; ++k) {
            const int q = mbase + k;
            const f32x2 M00 = m1[4 * q + 0], M01 = m1[4 * q + 1];
            const f32x2 M10 = m1[4 * q + 2], M11 = m1[4 * q + 3];
            const int msk = 1 << (k - 1);
            const int bit = (lane >> (k - 1)) & 1;
            f32x2 p0, p1;
            p0.x = __shfl_xor(r0.x, msk, 64); p0.y = __shfl_xor(r0.y, msk, 64);
            p1.x = __shfl_xor(r1.x, msk, 64); p1.y = __shfl_xor(r1.y, msk, 64);
            const f32x2 lo0 = bit ? p0 : r0, hi0 = bit ? r0 : p0;
            const f32x2 lo1 = bit ? p1 : r1, hi1 = bit ? r1 : p1;
            const f32x2 Ma  = bit ? M10 : M00;
            const f32x2 Mb  = bit ? M11 : M01;
            r0 = cmul(Ma, lo0) + cmul(Mb, hi0);
            r1 = cmul(Ma, lo1) + cmul(Mb, hi1);
        }
        const int j0 = g7i(u0), j1 = g7i(u1);
        if (w == 0)      { cc0[j0] = r0; cc0[j1] = r1; }
        else if (w == 1) { cc1[j0] = r0; cc1[j1] = r1; }
        else if (w == 2) { dd0[j0] = r0; dd0[j1] = r1; }
        else             { dd1[j0] = r0; dd1[j1] = r1; }
    }
    __syncthreads();

    // ---- Phase D: pack readout tables into global ws ----
    float* tb = ws + (size_t)b * 1024;
    if (tid < 128) {
        const int j = tid;
        const f32x2 c0 = cc0[j], c1 = cc1[j];
        tb[j +   0] = c0.x * c0.x + c0.y * c0.y;
        tb[j + 128] = c1.x * c1.x + c1.y * c1.y;
        tb[j + 256] = c0.x * c1.x + c0.y * c1.y;
        tb[j + 384] = c0.y * c1.x - c0.x * c1.y;
    } else {
        const int A = tid - 128;
        const f32x2 d0 = dd0[A], d1 = dd1[A];
        ((f32x4*)(tb + 512))[A] =
            f32x4{d0.x * d0.x + d0.y * d0.y,
                  d1.x * d1.x + d1.y * d1.y,
                  2.0f * (d0.x * d1.x + d0.y * d1.y),
                 -2.0f * (d0.y * d1.x - d0.x * d1.y)};
    }
}

// ---------------- kernel 2: fill-shaped streaming readout ----------------
// 1024 blocks x 256 thr; block = (batch, 32-row quarter) = 16 KB of output.
// No LDS, no barriers: 8 register loads (L2-hot) + 4 x {16 FMA + dwordx4 store}.
__global__ __launch_bounds__(256)
void qout_kernel(const float* __restrict__ ws, float* __restrict__ out)
{
    const int b    = blockIdx.x >> 2;
    const int qtr  = blockIdx.x & 3;
    const int tid  = threadIdx.x;
    const int w    = tid >> 6;          // wave 0..3
    const int lane = tid & 63;
    const int h    = lane >> 5;         // 0 = even rows, 1 = odd rows (Gray-flipped)
    const int s    = lane & 31;         // col block: 4s..4s+3

    const float* tb = ws + (size_t)b * 1024;
    const f32x4 fx = *(const f32x4*)(tb +   0 + 4 * s);
    const f32x4 fy = *(const f32x4*)(tb + 128 + 4 * s);
    const f32x4 fz = *(const f32x4*)(tb + 256 + 4 * s);
    const f32x4 fw = *(const f32x4*)(tb + 384 + 4 * s);
    const f32x4* eA = (const f32x4*)(tb + 512);

    const int row0 = 32 * qtr + 8 * w + h;          // first row of this half-wave
    const f32x4 e0 = eA[row0 + 0];                  // broadcast lines (L1/L2 hit)
    const f32x4 e1 = eA[row0 + 2];
    const f32x4 e2 = eA[row0 + 4];
    const f32x4 e3 = eA[row0 + 6];

    const int col = h ? (124 - 4 * s) : (4 * s);    // odd rows: m = j ^ 127, reversed
    float* op = out + (size_t)b * DIM + row0 * 128 + col;

    f32x4 o;
    o = e0.x * fx + e0.y * fy + e0.z * fz + e0.w * fw;
    if (h) o = f32x4{o.w, o.z, o.y, o.x};
    *(f32x4*)(op + 0 * 256) = o;
    o = e1.x * fx + e1.y * fy + e1.z * fz + e1.w * fw;
    if (h) o = f32x4{o.w, o.z, o.y, o.x};
    *(f32x4*)(op + 1 * 256) = o;
    o = e2.x * fx + e2.y * fy + e2.z * fz + e2.w * fw;
    if (h) o = f32x4{o.w, o.z, o.y, o.x};
    *(f32x4*)(op + 2 * 256) = o;
    o = e3.x * fx + e3.y * fy + e3.z * fz + e3.w * fw;
    if (h) o = f32x4{o.w, o.z, o.y, o.x};
    *(f32x4*)(op + 3 * 256) = o;
}

extern "C" void kernel_launch(void* const* d_in, const int* in_sizes, int n_in,
                              void* d_out, int out_size, void* d_ws, size_t ws_size,
                              hipStream_t stream) {
    const float* latent  = (const float*)d_in[0];   // [256][14]
    const float* weights = (const float*)d_in[1];   // [84]
    float* out = (float*)d_out;                     // [256][16384]
    float* ws  = (float*)d_ws;                      // >= 1 MB scratch

    const int B = in_sizes[0] / NQ;                 // 256
    qtab_kernel<<<B,     256, 0, stream>>>(latent, weights, ws);
    qout_kernel<<<B * 4, 256, 0, stream>>>(ws, out);
}

// Round 9
// 11.390 us; speedup vs baseline: 1.3086x; 1.3086x over previous
//
#include <hip/hip_runtime.h>

// 14-qubit statevector sim, batch 256 — rank-2 separable collapsed form.
// Single kernel, one block per batch element (256 x 1024), 2 barriers total.
//
// Validated math (rounds 0-7, absmax <= 4.9e-4 vs 8.67e-3 threshold):
//   s0 = product state (fused initial-RY + layer-0 RY/RZ/RY per qubit),
//   CNOT chain == Gray map g(l) = l ^ (l>>1), layer-1 fuses to one 2x2 per qubit,
//   final state rank-2 separable:
//     s2[m_hi,m_lo] = d0[m_hi] c0[m_lo] + d1[m_hi] c1[m_lo]
//   c_p/d_p: 128-vectors via 7 butterfly levels in one wave (__shfl_xor),
//   readout out[A*128+m] = e(A) . f(m ^ 127*(A&1)), odd rows = reversed f32x4
//   stores (j-block 4s..4s+3 is shared, consumed in reverse).
//
// This round (vs round 7): SPLIT 2->1 (prologue once per batch element),
// Phase B fused into C-init (g7(u^1)=g7(u)^1 shares 6 of 7 product factors),
// Phase D fused into E (f/e computed in-register at the consumer).

typedef float f32x2 __attribute__((ext_vector_type(2)));
typedef float f32x4 __attribute__((ext_vector_type(4)));

constexpr int NQ  = 14;
constexpr int DIM = 1 << NQ;       // 16384
constexpr int NT  = 1024;

__device__ __forceinline__ f32x2 cmul(f32x2 a, f32x2 b) {
    return f32x2{a.x * b.x - a.y * b.y, a.x * b.y + a.y * b.x};
}
__device__ __forceinline__ int g7(int x)  { return x ^ (x >> 1); }
__device__ __forceinline__ int g7i(int x) { x ^= x >> 1; x ^= x >> 2; x ^= x >> 4; return x; }

__global__ __launch_bounds__(NT)
void qsim_kernel(const float* __restrict__ latent,
                 const float* __restrict__ weights,
                 float* __restrict__ out)
{
    __shared__ f32x2 vq [2 * NQ];      // layer-0 fused columns (qubit q: vq[2q+bit])
    __shared__ f32x2 m1 [4 * NQ];      // layer-1 fused 2x2 per qubit
    __shared__ f32x2 cc0[128], cc1[128], dd0[128], dd1[128];   // readout order

    const int b   = blockIdx.x;
    const int tid = threadIdx.x;

    // ---- Phase A: fused per-qubit gate parameters ----
    if (tid < NQ) {
        const int q = tid;
        const float a = weights[3 * q] + 3.14159265358979323846f * latent[b * NQ + q];
        const float t = weights[3 * q + 1];
        const float c = weights[3 * q + 2];
        float ct, stt, cp, sp, cm, sm;
        __sincosf(0.5f * t, &stt, &ct);
        __sincosf(0.5f * (a + c), &sp, &cp);
        __sincosf(0.5f * (a - c), &sm, &cm);
        vq[2 * q + 0] = f32x2{ct * cp, -stt * cm};
        vq[2 * q + 1] = f32x2{ct * sp,  stt * sm};
    } else if (tid >= 64 && tid < 64 + NQ) {
        const int q = tid - 64;
        const float a = weights[3 * NQ + 3 * q];
        const float t = weights[3 * NQ + 3 * q + 1];
        const float c = weights[3 * NQ + 3 * q + 2];
        float ct, stt, cp, sp, cm, sm;
        __sincosf(0.5f * t, &stt, &ct);
        __sincosf(0.5f * (a + c), &sp, &cp);
        __sincosf(0.5f * (a - c), &sm, &cm);
        m1[4 * q + 0] = f32x2{ ct * cp, -stt * cm};
        m1[4 * q + 1] = f32x2{-ct * sp,  stt * sm};
        m1[4 * q + 2] = f32x2{ ct * sp,  stt * sm};
        m1[4 * q + 3] = f32x2{ ct * cp,  stt * cm};
    }
    __syncthreads();

    // ---- Phase C (waves 0-3): product init (B fused) + 7 butterfly levels ----
    if (tid < 256) {
        const int w    = tid >> 6;       // 0:c0 1:c1 2:d0 3:d1
        const int lane = tid & 63;
        const int u0   = 2 * lane;
        const int m0   = g7(u0);         // g7(u0+1) = m0 ^ 1
        const int base = (w >> 1) * 14;  // vq block: qubits 0-6 or 7-13

        // shared product over bits 1..6 of m0 (bit 6 flipped for the c1 pipeline)
        f32x2 t = vq[base + 2 + ((m0 >> 1) & 1)];
        #pragma unroll
        for (int j = 2; j < 6; ++j)
            t = cmul(t, vq[base + 2 * j + ((m0 >> j) & 1)]);
        const int b6 = ((m0 >> 6) & 1) ^ (w == 1 ? 1 : 0);
        t = cmul(t, vq[base + 12 + b6]);

        const int bit0 = m0 & 1;
        f32x2 r0, r1;
        if (w < 2) {                       // c pipelines: both columns live
            r0 = cmul(t, vq[base + bit0]);
            r1 = cmul(t, vq[base + (bit0 ^ 1)]);
        } else if (w == 2) {               // d0: y_0[u] = (u even) ? phi : 0
            r0 = cmul(t, vq[base + bit0]);
            r1 = f32x2{0.f, 0.f};
        } else {                           // d1: y_1[u] = (u odd) ? phi : 0
            r0 = f32x2{0.f, 0.f};
            r1 = cmul(t, vq[base + (bit0 ^ 1)]);
        }

        const int mbase = (w >> 1) * 7;

        {   // level 0: bit 0 of u lives in-register
            const f32x2 M00 = m1[4 * mbase + 0], M01 = m1[4 * mbase + 1];
            const f32x2 M10 = m1[4 * mbase + 2], M11 = m1[4 * mbase + 3];
            const f32x2 n0 = cmul(M00, r0) + cmul(M01, r1);
            const f32x2 n1 = cmul(M10, r0) + cmul(M11, r1);
            r0 = n0; r1 = n1;
        }
        #pragma unroll
        for (int k = 1; k < 7; ++k) {
            const int q = mbase + k;
            const f32x2 M00 = m1[4 * q + 0], M01 = m1[4 * q + 1];
            const f32x2 M10 = m1[4 * q + 2], M11 = m1[4 * q + 3];
            const int msk = 1 << (k - 1);
            const int bit = (lane >> (k - 1)) & 1;
            f32x2 p0, p1;
            p0.x = __shfl_xor(r0.x, msk, 64); p0.y = __shfl_xor(r0.y, msk, 64);
            p1.x = __shfl_xor(r1.x, msk, 64); p1.y = __shfl_xor(r1.y, msk, 64);
            const f32x2 lo0 = bit ? p0 : r0, hi0 = bit ? r0 : p0;
            const f32x2 lo1 = bit ? p1 : r1, hi1 = bit ? r1 : p1;
            const f32x2 Ma  = bit ? M10 : M00;
            const f32x2 Mb  = bit ? M11 : M01;
            r0 = cmul(Ma, lo0) + cmul(Mb, hi0);
            r1 = cmul(Ma, lo1) + cmul(Mb, hi1);
        }
        // store in readout order
        const int j0 = g7i(u0), j1 = g7i(u0 + 1);
        if (w == 0)      { cc0[j0] = r0; cc0[j1] = r1; }
        else if (w == 1) { cc1[j0] = r0; cc1[j1] = r1; }
        else if (w == 2) { dd0[j0] = r0; dd0[j1] = r1; }
        else             { dd1[j0] = r0; dd1[j1] = r1; }
    }
    __syncthreads();

    // ---- Phase E (all 16 waves): f/e built in-register, streamed stores ----
    {
        const int w    = tid >> 6;          // 0..15
        const int lane = tid & 63;
        const int h    = lane >> 5;         // 0 = even rows, 1 = odd (Gray-flipped)
        const int s    = lane & 31;         // j-block: cols 4s..4s+3

        const f32x4* c0v = (const f32x4*)cc0;   // pairs (x,y,x,y)
        const f32x4* c1v = (const f32x4*)cc1;
        const f32x4 c0a = c0v[2 * s], c0b = c0v[2 * s + 1];
        const f32x4 c1a = c1v[2 * s], c1b = c1v[2 * s + 1];

        const f32x4 fx = {c0a.x * c0a.x + c0a.y * c0a.y, c0a.z * c0a.z + c0a.w * c0a.w,
                          c0b.x * c0b.x + c0b.y * c0b.y, c0b.z * c0b.z + c0b.w * c0b.w};
        const f32x4 fy = {c1a.x * c1a.x + c1a.y * c1a.y, c1a.z * c1a.z + c1a.w * c1a.w,
                          c1b.x * c1b.x + c1b.y * c1b.y, c1b.z * c1b.z + c1b.w * c1b.w};
        const f32x4 fz = {c0a.x * c1a.x + c0a.y * c1a.y, c0a.z * c1a.z + c0a.w * c1a.w,
                          c0b.x * c1b.x + c0b.y * c1b.y, c0b.z * c1b.z + c0b.w * c1b.w};
        const f32x4 fw = {c0a.y * c1a.x - c0a.x * c1a.y, c0a.w * c1a.z - c0a.z * c1a.w,
                          c0b.y * c1b.x - c0b.x * c1b.y, c0b.w * c1b.z - c0b.z * c1b.w};

        const int row0 = 8 * w + h;
        const int col  = h ? (124 - 4 * s) : (4 * s);
        float* op = out + (size_t)b * DIM + row0 * 128 + col;

        #pragma unroll
        for (int t = 0; t < 4; ++t) {
            const int A = row0 + 2 * t;            // uniform per half-wave
            const f32x2 d0 = dd0[A], d1 = dd1[A];  // broadcast LDS reads
            const float ex = d0.x * d0.x + d0.y * d0.y;
            const float ey = d1.x * d1.x + d1.y * d1.y;
            const float ez =  2.0f * (d0.x * d1.x + d0.y * d1.y);
            const float ew = -2.0f * (d0.y * d1.x - d0.x * d1.y);
            f32x4 o = ex * fx + ey * fy + ez * fz + ew * fw;
            if (h) o = f32x4{o.w, o.z, o.y, o.x};  // reversed store for flipped rows
            *(f32x4*)(op + t * 256) = o;
        }
    }
}

extern "C" void kernel_launch(void* const* d_in, const int* in_sizes, int n_in,
                              void* d_out, int out_size, void* d_ws, size_t ws_size,
                              hipStream_t stream) {
    const float* latent  = (const float*)d_in[0];   // [256][14]
    const float* weights = (const float*)d_in[1];   // [84]
    float* out = (float*)d_out;                     // [256][16384]

    const int B = in_sizes[0] / NQ;                 // 256
    qsim_kernel<<<B, NT, 0, stream>>>(latent, weights, out);
}